// Round 6
// baseline (157.622 us; speedup 1.0000x reference)
//
#include <hip/hip_runtime.h>
#include <stdint.h>

// Problem constants: x (4, 8192, 512) f32, A/B (512, 64), h0 scalar.
#define NBATCH 4
#define LSEQ   8192
#define CH     512
#define ORDER  64
// KTAP=256 validated (R3-R5): tail negligible, absmax dominated by fp accum.
#define KTAP   256
#define RING   32            // output rows per thread / ring size (pow2)
#define CPB    256           // channels (=threads) per block

typedef _Float16 f16x2 __attribute__((ext_vector_type(2)));

__device__ __forceinline__ uint32_t packh2(_Float16 lo, _Float16 hi) {
    f16x2 v; v.x = lo; v.y = hi;
    return __builtin_bit_cast(uint32_t, v);
}

// acc += q.lo*k.lo + q.hi*k.hi  (fp32 accumulate, f16 operands) — 2 taps/instr.
__device__ __forceinline__ void dot2acc(float& acc, uint32_t q, uint32_t k) {
    asm("v_dot2_f32_f16 %0, %1, %2, %0" : "+v"(acc) : "v"(q), "v"(k));
}

// ---------------------------------------------------------------------------
// Kernel 1: impulse response of H(z) = b(z)/(1 + sum A_i z^-i), KTAP taps.
// Recursion in fp32; stored K quantized to f16 and PAIR-PACKED for dot2:
//   kp4[((t>>3)*CH + c)*4 + ((t>>1)&3)] = (f16(K[t&~1]) , f16(K[t|1]))
// i.e. one uint4 per (channel, 8-tap quarter). h0 folded into stored K[0].
// ---------------------------------------------------------------------------
__global__ __launch_bounds__(ORDER) void rtf_impulse(const float* __restrict__ A,
                                                     const float* __restrict__ B,
                                                     const float* __restrict__ h0,
                                                     uint32_t* __restrict__ kp4) {
    const int c    = blockIdx.x;
    const int lane = threadIdx.x;
    const float a  = A[c * ORDER + lane];
    const float bc = B[c * ORDER + lane];
    const float h0v = h0[0];

    float s = 0.0f;
    float yprev = 0.0f;   // stored value of the even tap of the current pair (lane 0)
    for (int t = 0; t < KTAP; ++t) {
        const float s1 = __shfl(s, 0);
        const float bt = (t < ORDER) ? __shfl(bc, t) : 0.0f;
        const float y  = bt + s1;                    // true K[t] (recursion value)
        float su = __shfl_down(s, 1);
        if (lane == ORDER - 1) su = 0.0f;
        s = su - a * y;
        if (lane == 0) {
            const float yq = (t == 0) ? (y + h0v) : y;   // stored (h0 fold)
            if ((t & 1) == 0) {
                yprev = yq;
            } else {
                kp4[((size_t)(t >> 3) * CH + c) * 4 + ((t >> 1) & 3)] =
                    packh2((_Float16)yprev, (_Float16)yq);
            }
        }
    }
}

// ---------------------------------------------------------------------------
// Kernel 2: depthwise causal FIR + tanh-GELU, f16 dot2 inner loop.
//   out[b,n,c] = gelu( sum_{t<KTAP} K[c,t] * x[b,n-t,c] )   (x[<0]=0)
// R5 skeleton (32-row ring, 8-tap quarters, double-buffered prefetch, XCD
// swizzle, fast gelu) with the ring storing PACKED PAIRS:
//   Qr[(m-n0)&31] = (f16 x[m], f16 x[m-1])   -> one v_dot2 covers 2 taps.
// Per pair p (t=2p): acc[r] += dot2(Qr[(r-2p)&31], Kpair[p]).
// Row m's pack needs x[m-1] (next batch's first row) for its hi half -> that
// one insert is DEFERRED to the next quarter's top via an f16 carry register;
// at the very first quarter the deferred insert is an idempotent rewrite of
// slot 0 (hcarry primed to f16(x[n0])). All array indices compile-time; no
// address-taken locals (R3 lesson).
// ---------------------------------------------------------------------------
__global__ __launch_bounds__(CPB) void fir_gelu(const float* __restrict__ x,
                                                const uint32_t* __restrict__ kp4,
                                                float* __restrict__ out) {
    const int h       = blockIdx.x;
    const int logical = ((h & 7) << 8) | (h >> 3);   // XCD k <- slab k (T1)
    const int tile    = logical & 255;
    const int sl      = logical >> 8;
    const int cb      = sl & 1;
    const int b       = sl >> 1;

    const int c  = cb * CPB + threadIdx.x;
    const int n0 = tile * RING;
    const float* xb = x + (size_t)b * LSEQ * CH + c;
    const uint4* kp4v = (const uint4*)kp4;   // 4 packed k-pairs per (quarter, channel)

    float    acc[RING];
    uint32_t Qr[RING];     // packed (x[m], x[m-1]) pairs, slot (m-n0)&31
    float    px[2][8];     // prefetched fp32 x rows for next quarter's inserts
    uint32_t kq[2][4];     // packed k pairs, current/next quarter
    _Float16 hq[8];        // f16 of px[cur] batch
    _Float16 hcarry;       // f16 of previous batch's last row

#pragma unroll
    for (int r = 0; r < RING; ++r) acc[r] = 0.0f;

    // ---- prologue: ring init (rows n0-1 .. n0+31), px/k for quarter 0 ----
    {
        const float xm1 = (n0 > 0) ? xb[(size_t)(n0 - 1) * CH] : 0.0f;
        _Float16 prev = (_Float16)xm1;
#pragma unroll
        for (int i = 0; i < RING; ++i) {
            const _Float16 curv = (_Float16)xb[(size_t)(n0 + i) * CH];
            Qr[i] = packh2(curv, prev);
            prev = curv;
            if (i == 0) hcarry = curv;    // f16(x[n0]) primes the deferred insert
        }
        const uint4 kt = kp4v[c];         // quarter 0 (pairs 0..3)
        kq[0][0] = kt.x; kq[0][1] = kt.y; kq[0][2] = kt.z; kq[0][3] = kt.w;
#pragma unroll
        for (int g = 0; g < 8; ++g) {
            const int m = n0 - 1 - g;     // row inserted at tap g
            px[0][g] = (m >= 0) ? xb[(size_t)m * CH] : 0.0f;
        }
    }

    for (int tb = 0; tb < KTAP; tb += 32) {
#pragma unroll
        for (int q = 0; q < 4; ++q) {
            const int cur = q & 1;
            const int nxt = cur ^ 1;
            // f16 batch for this quarter's inserts (loads landed a quarter ago)
#pragma unroll
            for (int g = 0; g < 8; ++g) hq[g] = (_Float16)px[cur][g];
            // deferred insert: Q[n0-t0] = (prev batch last row, this batch row 0)
            Qr[(32 - 8 * q) & 31] = packh2(hcarry, hq[0]);
            // ---- prefetch next quarter ----
            const int tn = tb + 8 * (q + 1);
            if (tn < KTAP) {
                const uint4 kt = kp4v[(size_t)(tn >> 3) * CH + c];
                kq[nxt][0] = kt.x; kq[nxt][1] = kt.y;
                kq[nxt][2] = kt.z; kq[nxt][3] = kt.w;
#pragma unroll
                for (int g = 0; g < 8; ++g) {
                    const int m = n0 - tn - 1 - g;
                    px[nxt][g] = (m >= 0) ? xb[(size_t)m * CH] : 0.0f;
                }
            }
            // ---- 4 tap-pairs: 32 dot2 each ----
#pragma unroll
            for (int g = 0; g < 4; ++g) {
                const int tq = 8 * q + 2 * g;          // t mod 32, static
                const uint32_t kv = kq[cur][g];
#pragma unroll
                for (int r = 0; r < RING; ++r)
                    dot2acc(acc[r], Qr[(r - tq) & (RING - 1)], kv);
                // retire 2 slots that aged out of the window
                if (g < 3) {
                    Qr[(31 - tq) & 31] = packh2(hq[2 * g],     hq[2 * g + 1]);
                    Qr[(30 - tq) & 31] = packh2(hq[2 * g + 1], hq[2 * g + 2]);
                } else {
                    Qr[(31 - tq) & 31] = packh2(hq[6], hq[7]);
                    hcarry = hq[7];                    // hi half comes next quarter
                }
            }
        }
    }

    float* ob = out + ((size_t)b * LSEQ + n0) * CH + c;
#pragma unroll
    for (int r = 0; r < RING; ++r) {
        const float y = acc[r];
        // gelu(y) = y * e/(e+1), e = exp(2*0.79788456*(y + 0.044715 y^3))
        const float m2 = y * y;
        const float w  = fmaf(m2, 0.14270963f, 1.5957691f);
        const float e  = __expf(y * w);
        const float r1 = __builtin_amdgcn_rcpf(e + 1.0f);
        ob[(size_t)r * CH] = y - y * r1;
    }
}

extern "C" void kernel_launch(void* const* d_in, const int* in_sizes, int n_in,
                              void* d_out, int out_size, void* d_ws, size_t ws_size,
                              hipStream_t stream) {
    const float* x  = (const float*)d_in[0];
    const float* A  = (const float*)d_in[1];
    const float* B  = (const float*)d_in[2];
    const float* h0 = (const float*)d_in[3];
    float* out = (float*)d_out;
    uint32_t* kp4 = (uint32_t*)d_ws;   // (KTAP/2)*CH*4B = 256 KB scratch

    rtf_impulse<<<dim3(CH), dim3(ORDER), 0, stream>>>(A, B, h0, kp4);
    fir_gelu<<<dim3((LSEQ / RING) * (CH / CPB) * NBATCH), dim3(CPB), 0, stream>>>(x, kp4, out);
}

// Round 7
// 85.936 us; speedup vs baseline: 1.8342x; 1.8342x over previous
//
#include <hip/hip_runtime.h>
#include <stdint.h>

// Problem constants: x (4, 8192, 512) f32, A/B (512, 64), h0 scalar.
#define NBATCH 4
#define LSEQ   8192
#define CH     512
#define ORDER  64
#define KTAP   256           // validated R3-R6: tail < 1e-5, threshold 5.86e-3

typedef _Float16 half8 __attribute__((ext_vector_type(8)));
typedef _Float16 half4 __attribute__((ext_vector_type(4)));
typedef float    f32x4 __attribute__((ext_vector_type(4)));

// Transposed/padded x geometry: column p = PAD0 + row, zeros outside [0,8192).
// PAD0 = 279: >= 271 history rows AND 2*(PAD0-15) % 16 == 0 so every B-fragment
// (8 consecutive f16 rows, r0 = n0+16j+8g-32w-15) is 16B-aligned.
#define PADP  8512           // 279 + 8192 + 41, multiple of 64
#define PAD0  279
#define NW    9              // tap windows: T0_w = 32w+15, w=0..8 covers t in [0,256) exactly once/row

#define AFRAG_HALFS  ((size_t)CH * NW * 64 * 8)        // 2,359,296 halves = 4.7 MB
#define XT_HALFS     ((size_t)CH * NBATCH * PADP)      // 17,432,576 halves = 34.9 MB
#define WS_NEED      ((AFRAG_HALFS + XT_HALFS) * 2)

// ---------------------------------------------------------------------------
// Kernel 1: IIR impulse response (transposed direct form II, proven R1-R6)
// -> per-channel MFMA A-fragments, lane-exact:
//   A_w[i][k] = Kx[32w+15+i-k], lane l: i=l&15, k=8*(l>>4)+e, h0 folded into Kx[0],
//   Kx zero outside [0,KTAP). Stored so kernel 3 reads one coalesced 16B/lane.
// ---------------------------------------------------------------------------
__global__ __launch_bounds__(ORDER) void rtf_afrag(const float* __restrict__ A,
                                                   const float* __restrict__ B,
                                                   const float* __restrict__ h0,
                                                   _Float16* __restrict__ afr) {
    const int c = blockIdx.x, lane = threadIdx.x;
    __shared__ float Ksh[KTAP];
    const float a  = A[c * ORDER + lane];
    const float bc = B[c * ORDER + lane];
    const float h0v = h0[0];
    float s = 0.0f;
    for (int t = 0; t < KTAP; ++t) {
        const float s1 = __shfl(s, 0);
        const float bt = (t < ORDER) ? __shfl(bc, t) : 0.0f;
        const float y  = bt + s1;
        float su = __shfl_down(s, 1);
        if (lane == ORDER - 1) su = 0.0f;
        s = su - a * y;
        if (lane == 0) Ksh[t] = (t == 0) ? (y + h0v) : y;
    }
    __syncthreads();
    const int i = lane & 15, g = lane >> 4;
    for (int w = 0; w < NW; ++w) {
        half8 hv;
#pragma unroll
        for (int e = 0; e < 8; ++e) {
            const int t = 32 * w + 15 + i - 8 * g - e;
            hv[e] = (_Float16)((t >= 0 && t < KTAP) ? Ksh[t] : 0.0f);
        }
        *reinterpret_cast<half8*>(afr + ((size_t)(c * NW + w) * 64 + lane) * 8) = hv;
    }
}

// ---------------------------------------------------------------------------
// Kernel 2: x (b,n,c) f32 -> xT (c*4+b, p) f16, zero-padded. 64x64 LDS tile.
// ---------------------------------------------------------------------------
__global__ __launch_bounds__(256) void xpose(const float* __restrict__ x,
                                             _Float16* __restrict__ xT) {
    const int p0 = blockIdx.x * 64;
    const int c0 = blockIdx.y * 64;
    const int b  = blockIdx.z;
    const int t  = threadIdx.x;
    __shared__ _Float16 tile[64][74];   // pad 74: bank-stride 37 (odd) on transposed reads
    const int cl = (t & 15) * 4;
    const int rl = t >> 4;
#pragma unroll
    for (int pass = 0; pass < 4; ++pass) {
        const int pl = rl + 16 * pass;
        const int r  = p0 + pl - PAD0;
        float4 v = {0.0f, 0.0f, 0.0f, 0.0f};
        if (r >= 0 && r < LSEQ)
            v = *reinterpret_cast<const float4*>(x + ((size_t)b * LSEQ + r) * CH + c0 + cl);
        tile[pl][cl + 0] = (_Float16)v.x;
        tile[pl][cl + 1] = (_Float16)v.y;
        tile[pl][cl + 2] = (_Float16)v.z;
        tile[pl][cl + 3] = (_Float16)v.w;
    }
    __syncthreads();
    const int pl2 = (t & 15) * 4;
#pragma unroll
    for (int pass = 0; pass < 4; ++pass) {
        const int cc = (t >> 4) + 16 * pass;
        half4 hv;
#pragma unroll
        for (int d = 0; d < 4; ++d) hv[d] = tile[pl2 + d][cc];
        *reinterpret_cast<half4*>(xT + ((size_t)((c0 + cc) * NBATCH + b)) * PADP + p0 + pl2) = hv;
    }
}

// ---------------------------------------------------------------------------
// Kernel 3: FIR as banded-Toeplitz MFMA + gelu.
// Block = 16 channels x 256 n (one tile), 4 waves x 4 channels, 9 MFMAs each:
//   acc[i][j] += A_w[i][k] * xT[col][PAD0 + n0+16j+8g+e-32w-15]
// C/D: col=lane&15 (j), row=(lane>>4)*4+reg (i), n = n0+16j+i.
// Epilogue: gelu -> LDS [16ch][256n] -> coalesced 64B stores.
// XCD swizzle: 4096 blocks, XCD k gets a contiguous 512-block slab (4 chgrps).
// ---------------------------------------------------------------------------
__global__ __launch_bounds__(256) void fir_mfma(const _Float16* __restrict__ xT,
                                                const _Float16* __restrict__ afr,
                                                float* __restrict__ out) {
    const int gid     = blockIdx.x;
    const int logical = (gid & 7) * 512 + (gid >> 3);   // bijective, 4096 % 8 == 0
    const int tile    = logical & 31;
    const int bb      = (logical >> 5) & 3;
    const int chgrp   = logical >> 7;                   // 0..31
    const int n0      = tile * 256;
    const int wid     = threadIdx.x >> 6;
    const int lane    = threadIdx.x & 63;
    const int j = lane & 15, g = lane >> 4;
    __shared__ float lds_out[16][258];                  // +2 pad: 2-way max on store-phase reads

    const int c0 = chgrp * 16 + wid * 4;
    const _Float16* xc0 = xT + ((size_t)((c0 + 0) * NBATCH + bb)) * PADP + PAD0;
    const _Float16* xc1 = xT + ((size_t)((c0 + 1) * NBATCH + bb)) * PADP + PAD0;
    const _Float16* xc2 = xT + ((size_t)((c0 + 2) * NBATCH + bb)) * PADP + PAD0;
    const _Float16* xc3 = xT + ((size_t)((c0 + 3) * NBATCH + bb)) * PADP + PAD0;
    const _Float16* af  = afr + (size_t)lane * 8;

    f32x4 acc0 = {0.f, 0.f, 0.f, 0.f}, acc1 = acc0, acc2 = acc0, acc3 = acc0;
#pragma unroll
    for (int w = 0; w < NW; ++w) {
        const int r0 = n0 + 16 * j + 8 * g - 32 * w - 15;   // >= -271; pad covers it
        const half8 b0 = *reinterpret_cast<const half8*>(xc0 + r0);
        const half8 b1 = *reinterpret_cast<const half8*>(xc1 + r0);
        const half8 b2 = *reinterpret_cast<const half8*>(xc2 + r0);
        const half8 b3 = *reinterpret_cast<const half8*>(xc3 + r0);
        const half8 a0 = *reinterpret_cast<const half8*>(af + (size_t)((c0 + 0) * NW + w) * 512);
        const half8 a1 = *reinterpret_cast<const half8*>(af + (size_t)((c0 + 1) * NW + w) * 512);
        const half8 a2 = *reinterpret_cast<const half8*>(af + (size_t)((c0 + 2) * NW + w) * 512);
        const half8 a3 = *reinterpret_cast<const half8*>(af + (size_t)((c0 + 3) * NW + w) * 512);
        acc0 = __builtin_amdgcn_mfma_f32_16x16x32_f16(a0, b0, acc0, 0, 0, 0);
        acc1 = __builtin_amdgcn_mfma_f32_16x16x32_f16(a1, b1, acc1, 0, 0, 0);
        acc2 = __builtin_amdgcn_mfma_f32_16x16x32_f16(a2, b2, acc2, 0, 0, 0);
        acc3 = __builtin_amdgcn_mfma_f32_16x16x32_f16(a3, b3, acc3, 0, 0, 0);
    }

    const int nr = 16 * j + 4 * g;
#define EPILOG(ACC, CI)                                                     \
    {                                                                       \
        _Pragma("unroll")                                                   \
        for (int r = 0; r < 4; ++r) {                                       \
            const float y  = ACC[r];                                        \
            const float m2 = y * y;                                         \
            const float wv = fmaf(m2, 0.14270963f, 1.5957691f);             \
            const float e  = __expf(y * wv);                                \
            const float rc = __builtin_amdgcn_rcpf(e + 1.0f);               \
            lds_out[wid * 4 + CI][nr + r] = y - y * rc;                     \
        }                                                                   \
    }
    EPILOG(acc0, 0) EPILOG(acc1, 1) EPILOG(acc2, 2) EPILOG(acc3, 3)
#undef EPILOG
    __syncthreads();

    const int cc = threadIdx.x & 15;
    const int nb = threadIdx.x >> 4;
    float* ob = out + ((size_t)bb * LSEQ + n0) * CH + chgrp * 16 + cc;
#pragma unroll
    for (int it = 0; it < 16; ++it) {
        const int nrel = nb + 16 * it;
        ob[(size_t)nrel * CH] = lds_out[cc][nrel];
    }
}

// ======================== FALLBACK (R5, proven 138us) =======================
#define RINGF 32
#define CPBF  256
__global__ __launch_bounds__(ORDER) void rtf_impulse_fb(const float* __restrict__ A,
                                                        const float* __restrict__ B,
                                                        const float* __restrict__ h0,
                                                        float* __restrict__ kt4) {
    const int c = blockIdx.x, lane = threadIdx.x;
    const float a = A[c * ORDER + lane], bc = B[c * ORDER + lane], h0v = h0[0];
    float s = 0.0f;
    for (int t = 0; t < KTAP; ++t) {
        const float s1 = __shfl(s, 0);
        const float bt = (t < ORDER) ? __shfl(bc, t) : 0.0f;
        const float y  = bt + s1;
        float su = __shfl_down(s, 1);
        if (lane == ORDER - 1) su = 0.0f;
        s = su - a * y;
        if (lane == 0) kt4[((size_t)(t >> 2) * CH + c) * 4 + (t & 3)] = (t == 0) ? (y + h0v) : y;
    }
}
__global__ __launch_bounds__(CPBF) void fir_gelu_fb(const float* __restrict__ x,
                                                    const float* __restrict__ kt4,
                                                    float* __restrict__ out) {
    const int h = blockIdx.x;
    const int logical = ((h & 7) << 8) | (h >> 3);
    const int tile = logical & 255, sl = logical >> 8;
    const int cb = sl & 1, b = sl >> 1;
    const int c = cb * CPBF + threadIdx.x;
    const int n0 = tile * RINGF;
    const float* xb = x + (size_t)b * LSEQ * CH + c;
    const float4* kt4v = (const float4*)kt4;
    float acc[RINGF]; float ring[RINGF]; float px[2][8]; float kbuf[2][8];
#pragma unroll
    for (int r = 0; r < RINGF; ++r) acc[r] = 0.0f;
#pragma unroll
    for (int i = 0; i < RINGF; ++i) ring[i] = xb[(size_t)(n0 + i) * CH];
    {
        const float4 ka = kt4v[(size_t)0 * CH + c];
        const float4 kb = kt4v[(size_t)1 * CH + c];
        kbuf[0][0] = ka.x; kbuf[0][1] = ka.y; kbuf[0][2] = ka.z; kbuf[0][3] = ka.w;
        kbuf[0][4] = kb.x; kbuf[0][5] = kb.y; kbuf[0][6] = kb.z; kbuf[0][7] = kb.w;
#pragma unroll
        for (int g2 = 0; g2 < 8; ++g2) {
            const int m = n0 - 1 - g2;
            px[0][g2] = (m >= 0) ? xb[(size_t)m * CH] : 0.0f;
        }
    }
    for (int tb = 0; tb < KTAP; tb += RINGF) {
#pragma unroll
        for (int q = 0; q < 4; ++q) {
            const int cur = q & 1, nxt = cur ^ 1;
            const int tn = tb + 8 * (q + 1);
            if (tn < KTAP) {
                const float4 ka = kt4v[(size_t)(tn >> 2) * CH + c];
                const float4 kb = kt4v[(size_t)((tn >> 2) + 1) * CH + c];
                kbuf[nxt][0] = ka.x; kbuf[nxt][1] = ka.y; kbuf[nxt][2] = ka.z; kbuf[nxt][3] = ka.w;
                kbuf[nxt][4] = kb.x; kbuf[nxt][5] = kb.y; kbuf[nxt][6] = kb.z; kbuf[nxt][7] = kb.w;
#pragma unroll
                for (int g2 = 0; g2 < 8; ++g2) {
                    const int m = n0 - tn - 1 - g2;
                    px[nxt][g2] = (m >= 0) ? xb[(size_t)m * CH] : 0.0f;
                }
            }
#pragma unroll
            for (int g2 = 0; g2 < 8; ++g2) {
                const int tq = 8 * q + g2;
                const float kv = kbuf[cur][g2];
#pragma unroll
                for (int r = 0; r < RINGF; ++r)
                    acc[r] = fmaf(kv, ring[(r - tq) & (RINGF - 1)], acc[r]);
                ring[(RINGF - 1 - tq) & (RINGF - 1)] = px[cur][g2];
            }
        }
    }
    float* ob = out + ((size_t)b * LSEQ + n0) * CH + c;
#pragma unroll
    for (int r = 0; r < RINGF; ++r) {
        const float y = acc[r];
        const float m2 = y * y;
        const float wv = fmaf(m2, 0.14270963f, 1.5957691f);
        const float e = __expf(y * wv);
        const float rc = __builtin_amdgcn_rcpf(e + 1.0f);
        ob[(size_t)r * CH] = y - y * rc;
    }
}

extern "C" void kernel_launch(void* const* d_in, const int* in_sizes, int n_in,
                              void* d_out, int out_size, void* d_ws, size_t ws_size,
                              hipStream_t stream) {
    const float* x  = (const float*)d_in[0];
    const float* A  = (const float*)d_in[1];
    const float* B  = (const float*)d_in[2];
    const float* h0 = (const float*)d_in[3];
    float* out = (float*)d_out;

    if (ws_size >= WS_NEED) {
        _Float16* afr = (_Float16*)d_ws;
        _Float16* xT  = afr + AFRAG_HALFS;
        rtf_afrag<<<dim3(CH), dim3(ORDER), 0, stream>>>(A, B, h0, afr);
        xpose<<<dim3(PADP / 64, CH / 64, NBATCH), dim3(256), 0, stream>>>(x, xT);
        fir_mfma<<<dim3(4096), dim3(256), 0, stream>>>(xT, afr, out);
    } else {
        float* kt4 = (float*)d_ws;  // 512 KB
        rtf_impulse_fb<<<dim3(CH), dim3(ORDER), 0, stream>>>(A, B, h0, kt4);
        fir_gelu_fb<<<dim3((LSEQ / RINGF) * (CH / CPBF) * NBATCH), dim3(CPBF), 0, stream>>>(x, kt4, out);
    }
}

// Round 8
// 60.735 us; speedup vs baseline: 2.5952x; 1.4149x over previous
//
#include <hip/hip_runtime.h>
#include <stdint.h>

// Problem constants: x (4, 8192, 512) f32, A/B (512, 64), h0 scalar.
#define NBATCH 4
#define LSEQ   8192
#define CH     512
#define ORDER  64
#define KTAP   256           // validated R3-R7: tail < 1e-5, threshold 5.86e-3

typedef _Float16 half8 __attribute__((ext_vector_type(8)));
typedef _Float16 half4 __attribute__((ext_vector_type(4)));
typedef float    f32x4 __attribute__((ext_vector_type(4)));

// Transposed/padded x geometry: column p = PAD0 + row, zeros outside [0,8192).
#define PADP  8512
#define PAD0  279
#define NW    9              // windows T0_w = 32w+15 cover t in [0,256) exactly once/row

#define AFRAG_HALFS  ((size_t)CH * NW * 64 * 8)        // 4.7 MB
#define XT_HALFS     ((size_t)CH * NBATCH * PADP)      // 34.9 MB
#define WS_NEED      ((AFRAG_HALFS + XT_HALFS) * 2)

#define NAPREP 128                       // afrag blocks (4 ch each)
#define NXPOSE (133 * 8 * NBATCH)        // xpose blocks (PADP/64 x CH/64 x B)

// ---------------------------------------------------------------------------
// Kernel 1 (fused prep): blocks [0,128) build per-channel MFMA A-fragments
// (IIR impulse response, 4 channels/block, one wave each — hides the serial
// recursion under the transpose); blocks [128, 128+4256) transpose x to
// xT[c*4+b][p] f16 zero-padded (64x64 LDS tile). Independent outputs.
// ---------------------------------------------------------------------------
__global__ __launch_bounds__(256) void prep(const float* __restrict__ A,
                                            const float* __restrict__ B,
                                            const float* __restrict__ h0,
                                            const float* __restrict__ x,
                                            _Float16* __restrict__ afr,
                                            _Float16* __restrict__ xT) {
    __shared__ float    Ksh[4][KTAP];
    __shared__ _Float16 tile[64][74];
    const int bid = blockIdx.x;
    if (bid < NAPREP) {
        // ---- A-fragment builder: A_w[i][k] = Kx[32w+15+i-k], lane l: i=l&15,
        //      k=8*(l>>4)+e; h0 folded into Kx[0]; Kx zero outside [0,KTAP).
        const int wv = threadIdx.x >> 6, lane = threadIdx.x & 63;
        const int c  = bid * 4 + wv;
        const float a  = A[c * ORDER + lane];
        const float bc = B[c * ORDER + lane];
        const float h0v = h0[0];
        float s = 0.0f;
        for (int t = 0; t < KTAP; ++t) {
            const float s1 = __shfl(s, 0);
            const float bt = (t < ORDER) ? __shfl(bc, t) : 0.0f;
            const float y  = bt + s1;
            float su = __shfl_down(s, 1);
            if (lane == ORDER - 1) su = 0.0f;
            s = su - a * y;
            if (lane == 0) Ksh[wv][t] = (t == 0) ? (y + h0v) : y;
        }
        __syncthreads();
        const int i = lane & 15, g = lane >> 4;
        for (int w = 0; w < NW; ++w) {
            half8 hv;
#pragma unroll
            for (int e = 0; e < 8; ++e) {
                const int t = 32 * w + 15 + i - 8 * g - e;
                hv[e] = (_Float16)((t >= 0 && t < KTAP) ? Ksh[wv][t] : 0.0f);
            }
            *reinterpret_cast<half8*>(afr + ((size_t)(c * NW + w) * 64 + lane) * 8) = hv;
        }
    } else {
        // ---- transpose: x (b,n,c) f32 -> xT (c*4+b, p) f16, zero-padded ----
        const int bid2 = bid - NAPREP;
        const int px   = bid2 % 133;
        const int cy   = (bid2 / 133) & 7;
        const int bz   = bid2 / (133 * 8);
        const int p0 = px * 64, c0 = cy * 64, t = threadIdx.x;
        const int cl = (t & 15) * 4;
        const int rl = t >> 4;
#pragma unroll
        for (int pass = 0; pass < 4; ++pass) {
            const int pl = rl + 16 * pass;
            const int r  = p0 + pl - PAD0;
            float4 v = {0.0f, 0.0f, 0.0f, 0.0f};
            if (r >= 0 && r < LSEQ)
                v = *reinterpret_cast<const float4*>(x + ((size_t)bz * LSEQ + r) * CH + c0 + cl);
            tile[pl][cl + 0] = (_Float16)v.x;
            tile[pl][cl + 1] = (_Float16)v.y;
            tile[pl][cl + 2] = (_Float16)v.z;
            tile[pl][cl + 3] = (_Float16)v.w;
        }
        __syncthreads();
        const int pl2 = (t & 15) * 4;
#pragma unroll
        for (int pass = 0; pass < 4; ++pass) {
            const int cc = (t >> 4) + 16 * pass;
            half4 hv;
#pragma unroll
            for (int d = 0; d < 4; ++d) hv[d] = tile[pl2 + d][cc];
            *reinterpret_cast<half4*>(xT + ((size_t)((c0 + cc) * NBATCH + bz)) * PADP + p0 + pl2) = hv;
        }
    }
}

// ---------------------------------------------------------------------------
// Kernel 2: FIR as banded-Toeplitz MFMA + gelu, LDS-staged x.
// Block = 16 ch x 1024 n (4 tiles of 256) x 1 batch. Grid 1024, chgrp-major
// XCD swizzle (each XCD owns 4 chgrps -> A-frags L2-resident, 590 KB/XCD).
// Stage: unique x window (16 ch x 1312 halves = 42 KB) -> LDS, coalesced.
// Main loop w-outer/tile-inner: A-frag loaded once per (c,w), used 4x;
// B-frags via ds_read_b128 (1:1 with MFMA). acc[4][4] f32x4, all static.
// Epilogue per tile: gelu -> lds_out (stride 260, float4 writes) -> 64B
// coalesced stores.
// ---------------------------------------------------------------------------
__global__ __launch_bounds__(256) void fir_mfma(const _Float16* __restrict__ xT,
                                                const _Float16* __restrict__ afr,
                                                float* __restrict__ out) {
    __shared__ _Float16 xs[16][1312];     // 42 KB: rows tg*1024-271 .. +1040
    __shared__ float    lds_out[16][260]; // 16.6 KB
    const int gid     = blockIdx.x;
    const int logical = (gid & 7) * 128 + (gid >> 3);   // bijective (1024%8==0)
    const int chgrp   = logical >> 5;                   // 0..31 (XCD-local slab)
    const int rem     = logical & 31;
    const int bb      = rem >> 3;
    const int tg      = rem & 7;

    // ---- stage x window: 16 groups of 16 threads, one channel each ----
    {
        const int grp = threadIdx.x >> 4;
        const int l16 = threadIdx.x & 15;
        const size_t rowbase = ((size_t)(chgrp * 16 + grp) * NBATCH + bb) * PADP
                             + (size_t)tg * 1024 + 8;   // abs col of xs[.][0]
#pragma unroll
        for (int it = 0; it < 11; ++it) {
            const int chunk = l16 + 16 * it;
            if (chunk < 164) {
                const half8 v = *reinterpret_cast<const half8*>(xT + rowbase + (size_t)chunk * 8);
                *reinterpret_cast<half8*>(&xs[grp][chunk * 8]) = v;
            }
        }
    }
    __syncthreads();

    const int wid = threadIdx.x >> 6, lane = threadIdx.x & 63;
    const int j = lane & 15, g = lane >> 4;
    const int c0 = chgrp * 16 + wid * 4;
    const _Float16* af = afr + (size_t)lane * 8;

    f32x4 acc[4][4];
#pragma unroll
    for (int ti = 0; ti < 4; ++ti)
#pragma unroll
        for (int q = 0; q < 4; ++q) acc[ti][q] = (f32x4){0.f, 0.f, 0.f, 0.f};

#pragma unroll
    for (int w = 0; w < NW; ++w) {
        half8 a[4];
#pragma unroll
        for (int q = 0; q < 4; ++q)
            a[q] = *reinterpret_cast<const half8*>(af + (size_t)((c0 + q) * NW + w) * 512);
        const int base = 16 * j + 8 * g - 32 * w + 256;   // LDS idx of B-frag, tile 0
#pragma unroll
        for (int ti = 0; ti < 4; ++ti) {
#pragma unroll
            for (int q = 0; q < 4; ++q) {
                const half8 bv = *reinterpret_cast<const half8*>(&xs[wid * 4 + q][base + 256 * ti]);
                acc[ti][q] = __builtin_amdgcn_mfma_f32_16x16x32_f16(a[q], bv, acc[ti][q], 0, 0, 0);
            }
        }
    }

    // ---- epilogue: per tile, gelu -> LDS transpose -> coalesced store ----
    const int ccs = threadIdx.x & 15, nb = threadIdx.x >> 4;
#pragma unroll
    for (int ti = 0; ti < 4; ++ti) {
        __syncthreads();
#pragma unroll
        for (int q = 0; q < 4; ++q) {
            f32x4 o;
#pragma unroll
            for (int r = 0; r < 4; ++r) {
                const float y  = acc[ti][q][r];
                const float m2 = y * y;
                const float wv = fmaf(m2, 0.14270963f, 1.5957691f);
                const float e  = __expf(y * wv);
                const float rc = __builtin_amdgcn_rcpf(e + 1.0f);
                o[r] = y - y * rc;
            }
            *reinterpret_cast<f32x4*>(&lds_out[wid * 4 + q][16 * j + 4 * g]) = o;
        }
        __syncthreads();
        const int n0 = tg * 1024 + ti * 256;
        float* ob = out + ((size_t)bb * LSEQ + n0) * CH + chgrp * 16 + ccs;
#pragma unroll
        for (int it = 0; it < 16; ++it) {
            const int nrel = nb + 16 * it;
            ob[(size_t)nrel * CH] = lds_out[ccs][nrel];
        }
    }
}

// ======================== FALLBACK (R5, proven 138us) =======================
#define RINGF 32
#define CPBF  256
__global__ __launch_bounds__(ORDER) void rtf_impulse_fb(const float* __restrict__ A,
                                                        const float* __restrict__ B,
                                                        const float* __restrict__ h0,
                                                        float* __restrict__ kt4) {
    const int c = blockIdx.x, lane = threadIdx.x;
    const float a = A[c * ORDER + lane], bc = B[c * ORDER + lane], h0v = h0[0];
    float s = 0.0f;
    for (int t = 0; t < KTAP; ++t) {
        const float s1 = __shfl(s, 0);
        const float bt = (t < ORDER) ? __shfl(bc, t) : 0.0f;
        const float y  = bt + s1;
        float su = __shfl_down(s, 1);
        if (lane == ORDER - 1) su = 0.0f;
        s = su - a * y;
        if (lane == 0) kt4[((size_t)(t >> 2) * CH + c) * 4 + (t & 3)] = (t == 0) ? (y + h0v) : y;
    }
}
__global__ __launch_bounds__(CPBF) void fir_gelu_fb(const float* __restrict__ x,
                                                    const float* __restrict__ kt4,
                                                    float* __restrict__ out) {
    const int h = blockIdx.x;
    const int logical = ((h & 7) << 8) | (h >> 3);
    const int tile = logical & 255, sl = logical >> 8;
    const int cb = sl & 1, b = sl >> 1;
    const int c = cb * CPBF + threadIdx.x;
    const int n0 = tile * RINGF;
    const float* xb = x + (size_t)b * LSEQ * CH + c;
    const float4* kt4v = (const float4*)kt4;
    float acc[RINGF]; float ring[RINGF]; float px[2][8]; float kbuf[2][8];
#pragma unroll
    for (int r = 0; r < RINGF; ++r) acc[r] = 0.0f;
#pragma unroll
    for (int i = 0; i < RINGF; ++i) ring[i] = xb[(size_t)(n0 + i) * CH];
    {
        const float4 ka = kt4v[(size_t)0 * CH + c];
        const float4 kb = kt4v[(size_t)1 * CH + c];
        kbuf[0][0] = ka.x; kbuf[0][1] = ka.y; kbuf[0][2] = ka.z; kbuf[0][3] = ka.w;
        kbuf[0][4] = kb.x; kbuf[0][5] = kb.y; kbuf[0][6] = kb.z; kbuf[0][7] = kb.w;
#pragma unroll
        for (int g2 = 0; g2 < 8; ++g2) {
            const int m = n0 - 1 - g2;
            px[0][g2] = (m >= 0) ? xb[(size_t)m * CH] : 0.0f;
        }
    }
    for (int tb = 0; tb < KTAP; tb += RINGF) {
#pragma unroll
        for (int q = 0; q < 4; ++q) {
            const int cur = q & 1, nxt = cur ^ 1;
            const int tn = tb + 8 * (q + 1);
            if (tn < KTAP) {
                const float4 ka = kt4v[(size_t)(tn >> 2) * CH + c];
                const float4 kb = kt4v[(size_t)((tn >> 2) + 1) * CH + c];
                kbuf[nxt][0] = ka.x; kbuf[nxt][1] = ka.y; kbuf[nxt][2] = ka.z; kbuf[nxt][3] = ka.w;
                kbuf[nxt][4] = kb.x; kbuf[nxt][5] = kb.y; kbuf[nxt][6] = kb.z; kbuf[nxt][7] = kb.w;
#pragma unroll
                for (int g2 = 0; g2 < 8; ++g2) {
                    const int m = n0 - tn - 1 - g2;
                    px[nxt][g2] = (m >= 0) ? xb[(size_t)m * CH] : 0.0f;
                }
            }
#pragma unroll
            for (int g2 = 0; g2 < 8; ++g2) {
                const int tq = 8 * q + g2;
                const float kv = kbuf[cur][g2];
#pragma unroll
                for (int r = 0; r < RINGF; ++r)
                    acc[r] = fmaf(kv, ring[(r - tq) & (RINGF - 1)], acc[r]);
                ring[(RINGF - 1 - tq) & (RINGF - 1)] = px[cur][g2];
            }
        }
    }
    float* ob = out + ((size_t)b * LSEQ + n0) * CH + c;
#pragma unroll
    for (int r = 0; r < RINGF; ++r) {
        const float y = acc[r];
        const float m2 = y * y;
        const float wv = fmaf(m2, 0.14270963f, 1.5957691f);
        const float e = __expf(y * wv);
        const float rc = __builtin_amdgcn_rcpf(e + 1.0f);
        ob[(size_t)r * CH] = y - y * rc;
    }
}

extern "C" void kernel_launch(void* const* d_in, const int* in_sizes, int n_in,
                              void* d_out, int out_size, void* d_ws, size_t ws_size,
                              hipStream_t stream) {
    const float* x  = (const float*)d_in[0];
    const float* A  = (const float*)d_in[1];
    const float* B  = (const float*)d_in[2];
    const float* h0 = (const float*)d_in[3];
    float* out = (float*)d_out;

    if (ws_size >= WS_NEED) {
        _Float16* afr = (_Float16*)d_ws;
        _Float16* xT  = afr + AFRAG_HALFS;
        prep<<<dim3(NAPREP + NXPOSE), dim3(256), 0, stream>>>(A, B, h0, x, afr, xT);
        fir_mfma<<<dim3(1024), dim3(256), 0, stream>>>(xT, afr, out);
    } else {
        float* kt4 = (float*)d_ws;  // 512 KB
        rtf_impulse_fb<<<dim3(CH), dim3(ORDER), 0, stream>>>(A, B, h0, kt4);
        fir_gelu_fb<<<dim3((LSEQ / RINGF) * (CH / CPBF) * NBATCH), dim3(CPBF), 0, stream>>>(x, kt4, out);
    }
}